// Round 9
// baseline (49.139 us; speedup 1.0000x reference)
//
#include <hip/hip_runtime.h>
#include <math.h>

// B=64, C=256, HW=256, HEADS=8, HEAD_DIM=256, HID=2048, TEMB=512
// Identity: einsum 'bhnm,bhcl->bhml' contracts n,c independently =>
// softmaxes sum to 1 => q,k irrelevant; pre-projection output is
// SC^2 * colsum of v over head_dim, constant over spatial l.
//
// R8 lesson: graph kernel->kernel boundaries cost ~10-12us each (drain +
// per-XCD L2 flush); R6 lesson: 256-way grid barriers cost ~13-15us.
// => ONE kernel, NO global sync: only per-b 4-way flag syncs (the true
// dependency) + a one-time 32-flag wait for the Wv colsums. Each b-group
// staggers independently; no convoy.
//
// Block (b,q), 1024 thr: MLP j-slice -> flag -> coef -> x-pass ->
// projection partial -> flag -> redundant per-b RMS -> stream x-quarter.

static constexpr float EPSV = 1e-6f;
static constexpr float SC2 = 1.0f / 256.0f;   // SC^2, SC = 256^-0.5

#define NTHR 1024

__device__ __forceinline__ float wave_sum(float v) {
    v += __shfl_xor(v, 1);  v += __shfl_xor(v, 2);
    v += __shfl_xor(v, 4);  v += __shfl_xor(v, 8);
    v += __shfl_xor(v, 16); v += __shfl_xor(v, 32);
    return v;
}

__device__ __forceinline__ void rel_flag(unsigned* f) {
    __hip_atomic_store(f, 1u, __ATOMIC_RELEASE, __HIP_MEMORY_SCOPE_AGENT);
}
__device__ __forceinline__ void spin_flag(unsigned* f) {
    while (!__hip_atomic_load(f, __ATOMIC_RELAXED, __HIP_MEMORY_SCOPE_AGENT))
        __builtin_amdgcn_s_sleep(1);
    (void)__hip_atomic_load(f, __ATOMIC_ACQUIRE, __HIP_MEMORY_SCOPE_AGENT);
}

__global__ void __launch_bounds__(NTHR) k_all(
    const float* __restrict__ x, const float* __restrict__ temb,
    const float* __restrict__ mlp_w, const float* __restrict__ mlp_b,
    const float* __restrict__ qkv_w, const float* __restrict__ out_w,
    const float* __restrict__ out_b, const float* __restrict__ onorm,
    float* __restrict__ out, float* __restrict__ ws)
{
    __shared__ float smem[12288];          // 48 KB, re-carved per phase
    unsigned* uf = (unsigned*)ws;          // flags (zeroed per call):
                                           //  p0: uf[blk*16], blk<256
                                           //  yp: uf[4096 + blk*16]
    float* scsh  = ws + 16384;             // [64 b][512 j]
    float* wvg   = ws + 49152;             // [8 h][256 c]
    float* ypart = ws + 51200;             // [4 q][64 b][256 c]

    const int blk = blockIdx.x, tid = threadIdx.x;
    const int wv = tid >> 6, lane = tid & 63;
    const int b = blk >> 2, q = blk & 3;

    // ========== P0: MLP j-slice [q*128,+128) (+ wvg slice if blk<32) =====
    {
        float* sl = smem;                  // [512] silu(temb[b])
        if (tid < 512) {
            float v = temb[b * 512 + tid];
            sl[tid] = v / (1.0f + expf(-v));
        }
        __syncthreads();
        int j0 = q * 128 + wv * 8;
        float acc[8] = {0, 0, 0, 0, 0, 0, 0, 0};
        const float* wb = mlp_w + (size_t)j0 * 512 + lane;
#pragma unroll
        for (int k = 0; k < 8; ++k) {
            float sv = sl[k * 64 + lane];
#pragma unroll
            for (int jj = 0; jj < 8; ++jj)
                acc[jj] = fmaf(wb[(size_t)jj * 512 + k * 64], sv, acc[jj]);
        }
#pragma unroll
        for (int jj = 0; jj < 8; ++jj) {
            float a = wave_sum(acc[jj]);
            if (lane == 0) scsh[b * 512 + j0 + jj] = a + mlp_b[j0 + jj];
        }
        if (blk < 32) {                    // wvg producer: (h, cq) slice
            int h = blk >> 2, cq = blk & 3;
            float* wsum = smem + 512;      // [16][64]
            const float* base = qkv_w +
                (size_t)(4096 + h * 256 + wv * 16) * 256 + cq * 64 + lane;
            float s = 0.f;
#pragma unroll
            for (int r = 0; r < 16; ++r) s += base[(size_t)r * 256];
            wsum[wv * 64 + lane] = s;
            __syncthreads();
            if (tid < 64) {
                float t = 0.f;
#pragma unroll
                for (int r = 0; r < 16; ++r) t += wsum[r * 64 + tid];
                wvg[h * 256 + cq * 64 + tid] = t;
            }
        }
        __syncthreads();
        if (tid == 0) rel_flag(uf + blk * 16);
    }

    // ---- wait: 4 MLP flags of this b + 32 wvg-producer flags ------------
    if (tid < 4) spin_flag(uf + (b * 4 + tid) * 16);
    else if (tid >= 64 && tid < 96) spin_flag(uf + (tid - 64) * 16);
    __syncthreads();

    // ========== P1: coef[c][h] = (1+scale)*Wv; ssh[h] = sum shift*Wv =====
    float* coef  = smem;                   // [256*8]   2048
    float* apart = smem + 2048;            // [16][64][9] 9216
    float* ofl   = smem + 11264;           // [512]
    float* ssh   = smem + 11776;           // [8]
    float* parts = smem + 11784;           // [32]

    if (tid < 256) {
        int c = tid;
        float sc = 1.0f + scsh[b * 512 + c];
        float sh = scsh[b * 512 + 256 + c];
#pragma unroll
        for (int h = 0; h < 8; ++h) {
            float wvv = wvg[h * 256 + c];
            coef[c * 8 + h] = sc * wvv;
            float sv = wave_sum(sh * wvv);
            if (lane == 0) parts[wv * 8 + h] = sv;
        }
    }
    __syncthreads();
    if (tid < 8)
        ssh[tid] = parts[tid] + parts[8 + tid] + parts[16 + tid] + parts[24 + tid];

    // ========== P2: x-pass over m-quarter q ==============================
    {
        int m = tid & 63, cg = tid >> 6;   // 16 c-groups x 16 c
        float A[8] = {0, 0, 0, 0, 0, 0, 0, 0};
        float ss2 = 0.f;
        const float* xb = x + (size_t)b * 65536 + q * 64 + m;
#pragma unroll
        for (int ci = 0; ci < 16; ++ci) {
            int c = cg * 16 + ci;
            float xv = xb[(size_t)c * 256];
            ss2 = fmaf(xv, xv, ss2);
            const float4 c0 = *reinterpret_cast<const float4*>(&coef[c * 8]);
            const float4 c1 = *reinterpret_cast<const float4*>(&coef[c * 8 + 4]);
            A[0] = fmaf(xv, c0.x, A[0]); A[1] = fmaf(xv, c0.y, A[1]);
            A[2] = fmaf(xv, c0.z, A[2]); A[3] = fmaf(xv, c0.w, A[3]);
            A[4] = fmaf(xv, c1.x, A[4]); A[5] = fmaf(xv, c1.y, A[5]);
            A[6] = fmaf(xv, c1.z, A[6]); A[7] = fmaf(xv, c1.w, A[7]);
        }
        float* ap = apart + ((size_t)cg * 64 + m) * 9;
#pragma unroll
        for (int h = 0; h < 8; ++h) ap[h] = A[h];
        ap[8] = ss2;
    }
    __syncthreads();
    if (tid < 64) {
        int m = tid;
        float fin[9] = {0, 0, 0, 0, 0, 0, 0, 0, 0};
#pragma unroll
        for (int g = 0; g < 16; ++g)
#pragma unroll
            for (int i = 0; i < 9; ++i)
                fin[i] += apart[((size_t)g * 64 + m) * 9 + i];
        float inv = rsqrtf(fin[8] * (1.0f / 256.0f) + EPSV);
#pragma unroll
        for (int h = 0; h < 8; ++h)
            ofl[h * 64 + m] = SC2 * fmaf(inv, fin[h], ssh[h]);
    }
    __syncthreads();

    // ========== P3: projection partial -> ypart[q][b][c] =================
    {
        const float4* of4 = reinterpret_cast<const float4*>(ofl);  // [128]
#pragma unroll
        for (int g4 = 0; g4 < 4; ++g4) {
            int c0 = wv * 16 + g4 * 4;
            float a[4] = {0, 0, 0, 0};
#pragma unroll
            for (int cc = 0; cc < 4; ++cc) {
                int c = c0 + cc;
#pragma unroll
                for (int k = 0; k < 2; ++k) {
                    int idx = k * 64 + lane;       // 0..127
                    int h = idx >> 4, mm = (idx & 15) * 4;
                    const float4 w4 = *reinterpret_cast<const float4*>(
                        &out_w[(size_t)c * 2048 + h * 256 + q * 64 + mm]);
                    float4 ov = of4[idx];
                    a[cc] = fmaf(w4.x, ov.x, a[cc]);
                    a[cc] = fmaf(w4.y, ov.y, a[cc]);
                    a[cc] = fmaf(w4.z, ov.z, a[cc]);
                    a[cc] = fmaf(w4.w, ov.w, a[cc]);
                }
            }
#pragma unroll
            for (int cc = 0; cc < 4; ++cc) {
                float s = wave_sum(a[cc]);
                if (lane == 0)
                    ypart[(size_t)q * 16384 + b * 256 + c0 + cc] = s;
            }
        }
        __syncthreads();
        if (tid == 0) rel_flag(uf + 4096 + blk * 16);
    }

    // ---- wait: 4 ypart flags of this b ----------------------------------
    if (tid < 4) spin_flag(uf + 4096 + (b * 4 + tid) * 16);
    __syncthreads();

    // ========== P4: redundant per-b RMS + g; stream out quarter ==========
    {
        float* g    = smem;                // [256]
        float* wred = smem + 320;          // [4]
        float yb = 0.f;
        if (tid < 256) {
            yb = out_b[tid] +
                 ypart[b * 256 + tid] + ypart[16384 + b * 256 + tid] +
                 ypart[32768 + b * 256 + tid] + ypart[49152 + b * 256 + tid];
            float v2 = wave_sum(yb * yb);
            if (lane == 0) wred[wv] = v2;
        }
        __syncthreads();
        float inv2 = rsqrtf((wred[0] + wred[1] + wred[2] + wred[3]) *
                            (1.0f / 256.0f) + EPSV);
        if (tid < 256) g[tid] = yb * inv2 * onorm[tid];
        __syncthreads();

        // out[b, c, q*64 .. +63] = x + g[c]; float4 idx = c*64 + q*16 + i
        const float4* xx = reinterpret_cast<const float4*>(x) + (size_t)b * 16384;
        float4* oo = reinterpret_cast<float4*>(out) + (size_t)b * 16384;
#pragma unroll
        for (int r = 0; r < 4; ++r) {
            int c = r * 64 + (tid >> 4);
            int i = tid & 15;
            size_t idx = (size_t)c * 64 + q * 16 + i;
            float4 xv = xx[idx];
            float gg = g[c];
            oo[idx] = make_float4(xv.x + gg, xv.y + gg, xv.z + gg, xv.w + gg);
        }
    }
}

extern "C" void kernel_launch(void* const* d_in, const int* in_sizes, int n_in,
                              void* d_out, int out_size, void* d_ws, size_t ws_size,
                              hipStream_t stream) {
    const float* x     = (const float*)d_in[0];
    const float* temb  = (const float*)d_in[1];
    const float* mlp_w = (const float*)d_in[2];
    const float* mlp_b = (const float*)d_in[3];
    const float* qkv_w = (const float*)d_in[4];
    const float* out_w = (const float*)d_in[5];
    const float* out_b = (const float*)d_in[6];
    const float* onorm = (const float*)d_in[7];
    float* out = (float*)d_out;
    float* ws  = (float*)d_ws;

    // zero the flag region each call (SDMA fill node ~free; R3 measured)
    hipMemsetAsync(ws, 0, 32768, stream);
    k_all<<<256, NTHR, 0, stream>>>(x, temb, mlp_w, mlp_b, qkv_w,
                                    out_w, out_b, onorm, out, ws);
}

// Round 10
// 40.942 us; speedup vs baseline: 1.2002x; 1.2002x over previous
//
#include <hip/hip_runtime.h>
#include <math.h>

// B=64, C=256, HW=256, HEADS=8, HEAD_DIM=256, HID=2048, TEMB=512
// Identity: einsum 'bhnm,bhcl->bhml' contracts n,c independently =>
// softmaxes sum to 1 => q,k irrelevant; pre-projection output is
// SC^2 * colsum of v over head_dim, constant over spatial l.
//
// R8 (35us): K0 prep -> K1 body -> K2 fin, no syncs.
// R9 (49us): single kernel, but global 32-flag wait convoyed everything.
// This round: K0 prep -> K1 body+fin fused with ONLY a per-b 4-flag
// local sync (adjacent blocks, no global convoy, one acquire).

static constexpr float EPSV = 1e-6f;
static constexpr float SC2 = 1.0f / 256.0f;   // SC^2, SC = 256^-0.5

__device__ __forceinline__ float wave_sum(float v) {
    v += __shfl_xor(v, 1);  v += __shfl_xor(v, 2);
    v += __shfl_xor(v, 4);  v += __shfl_xor(v, 8);
    v += __shfl_xor(v, 16); v += __shfl_xor(v, 32);
    return v;
}

__device__ __forceinline__ void rel_flag(unsigned* f) {
    __hip_atomic_store(f, 1u, __ATOMIC_RELEASE, __HIP_MEMORY_SCOPE_AGENT);
}
__device__ __forceinline__ void spin_flag(unsigned* f) {
    while (!__hip_atomic_load(f, __ATOMIC_RELAXED, __HIP_MEMORY_SCOPE_AGENT))
        __builtin_amdgcn_s_sleep(1);
    (void)__hip_atomic_load(f, __ATOMIC_ACQUIRE, __HIP_MEMORY_SCOPE_AGENT);
}

// ---------------- K0: time-MLP + Wv column-sums (R8 verbatim) -----------
__global__ void __launch_bounds__(256) k0_prep(
    const float* __restrict__ temb, const float* __restrict__ mlp_w,
    const float* __restrict__ mlp_b, const float* __restrict__ qkv_w,
    float* __restrict__ scsh, float* __restrict__ wvg)
{
    const int blk = blockIdx.x, tid = threadIdx.x;
    const int wv = tid >> 6, lane = tid & 63;
    if (blk < 1024) {
        int b = blk >> 4, jg = blk & 15;
        __shared__ float sl[512];
        float v0 = temb[b * 512 + tid];
        float v1 = temb[b * 512 + 256 + tid];
        sl[tid] = v0 / (1.0f + expf(-v0));
        sl[256 + tid] = v1 / (1.0f + expf(-v1));
        __syncthreads();
        int j0 = jg * 32 + wv * 8;
        float acc[8] = {0, 0, 0, 0, 0, 0, 0, 0};
        const float* wb = mlp_w + (size_t)j0 * 512 + lane;
#pragma unroll
        for (int k = 0; k < 8; ++k) {
            float sv = sl[k * 64 + lane];
#pragma unroll
            for (int jj = 0; jj < 8; ++jj)
                acc[jj] = fmaf(wb[(size_t)jj * 512 + k * 64], sv, acc[jj]);
        }
#pragma unroll
        for (int jj = 0; jj < 8; ++jj) {
            float a = wave_sum(acc[jj]);
            if (lane == 0) scsh[b * 512 + j0 + jj] = a + mlp_b[j0 + jj];
        }
    } else {
        int w = blk - 1024;                // 0..31
        int h = w >> 2, cq = w & 3;
        __shared__ float sm[256];
        const float* base =
            qkv_w + (size_t)(4096 + h * 256 + wv * 64) * 256 + cq * 64 + lane;
        float s = 0.f;
#pragma unroll 8
        for (int r = 0; r < 64; ++r) s += base[(size_t)r * 256];
        sm[wv * 64 + lane] = s;
        __syncthreads();
        if (tid < 64)
            wvg[h * 256 + cq * 64 + tid] =
                sm[tid] + sm[64 + tid] + sm[128 + tid] + sm[192 + tid];
    }
}

// ---------------- K1: body + fin, per-b local sync ----------------------
// grid 256 = (b, q = m-quarter); 1024 threads.
__global__ void __launch_bounds__(1024) k1_body(
    const float* __restrict__ x, const float* __restrict__ scsh,
    const float* __restrict__ wvg, const float* __restrict__ out_w,
    const float* __restrict__ out_b, const float* __restrict__ onorm,
    float* __restrict__ out, float* __restrict__ ws)
{
    const int blk = blockIdx.x, tid = threadIdx.x;
    const int wv = tid >> 6, lane = tid & 63;
    const int b = blk >> 2, q = blk & 3;

    unsigned* uf = (unsigned*)ws;          // flags: uf[blk*16]
    float* ypart = ws + 4096;              // [4 q][64 b][256 c]

    __shared__ float coef[256 * 8];        // [c][h]  8 KB
    __shared__ float apart[16 * 64 * 9];   // [cg][m][A0..7,ss2]  36 KB
    __shared__ float ofl[512];             // [h][m]  2 KB
    __shared__ float ssh[8];
    __shared__ float parts[4 * 8];

    // ---- P1: coef[c][h] = (1+scale)*Wv; ssh[h] = sum_c shift*Wv ----
    if (tid < 256) {
        int c = tid;
        float sc = 1.0f + scsh[b * 512 + c];
        float sh = scsh[b * 512 + 256 + c];
#pragma unroll
        for (int h = 0; h < 8; ++h) {
            float wvv = wvg[h * 256 + c];
            coef[c * 8 + h] = sc * wvv;
            float sv = wave_sum(sh * wvv);
            if (lane == 0) parts[wv * 8 + h] = sv;
        }
    }
    __syncthreads();
    if (tid < 8)
        ssh[tid] = parts[tid] + parts[8 + tid] + parts[16 + tid] + parts[24 + tid];

    // ---- P2: x-pass over m-quarter q ----
    {
        int m = tid & 63, cg = tid >> 6;   // 16 c-groups x 16 c
        float A[8] = {0, 0, 0, 0, 0, 0, 0, 0};
        float ss2 = 0.f;
        const float* xb = x + (size_t)b * 65536 + q * 64 + m;
#pragma unroll
        for (int ci = 0; ci < 16; ++ci) {
            int c = cg * 16 + ci;
            float xv = xb[(size_t)c * 256];
            ss2 = fmaf(xv, xv, ss2);
            const float4 c0 = *reinterpret_cast<const float4*>(&coef[c * 8]);
            const float4 c1 = *reinterpret_cast<const float4*>(&coef[c * 8 + 4]);
            A[0] = fmaf(xv, c0.x, A[0]); A[1] = fmaf(xv, c0.y, A[1]);
            A[2] = fmaf(xv, c0.z, A[2]); A[3] = fmaf(xv, c0.w, A[3]);
            A[4] = fmaf(xv, c1.x, A[4]); A[5] = fmaf(xv, c1.y, A[5]);
            A[6] = fmaf(xv, c1.z, A[6]); A[7] = fmaf(xv, c1.w, A[7]);
        }
        float* ap = apart + ((size_t)cg * 64 + m) * 9;
#pragma unroll
        for (int h = 0; h < 8; ++h) ap[h] = A[h];
        ap[8] = ss2;
    }
    __syncthreads();
    if (tid < 64) {
        int m = tid;
        float fin[9] = {0, 0, 0, 0, 0, 0, 0, 0, 0};
#pragma unroll
        for (int g = 0; g < 16; ++g)
#pragma unroll
            for (int i = 0; i < 9; ++i)
                fin[i] += apart[((size_t)g * 64 + m) * 9 + i];
        float inv = rsqrtf(fin[8] * (1.0f / 256.0f) + EPSV);
#pragma unroll
        for (int h = 0; h < 8; ++h)
            ofl[h * 64 + m] = SC2 * fmaf(inv, fin[h], ssh[h]);
    }
    __syncthreads();

    // ---- P3: projection partial -> ypart[q][b][c] ----
    {
        const float4* of4 = reinterpret_cast<const float4*>(ofl);  // [128]
#pragma unroll
        for (int g4 = 0; g4 < 4; ++g4) {
            int c0 = wv * 16 + g4 * 4;
            float a[4] = {0, 0, 0, 0};
#pragma unroll
            for (int cc = 0; cc < 4; ++cc) {
                int c = c0 + cc;
#pragma unroll
                for (int k = 0; k < 2; ++k) {
                    int idx = k * 64 + lane;       // 0..127
                    int h = idx >> 4, mm = (idx & 15) * 4;
                    const float4 w4 = *reinterpret_cast<const float4*>(
                        &out_w[(size_t)c * 2048 + h * 256 + q * 64 + mm]);
                    float4 ov = of4[idx];
                    a[cc] = fmaf(w4.x, ov.x, a[cc]);
                    a[cc] = fmaf(w4.y, ov.y, a[cc]);
                    a[cc] = fmaf(w4.z, ov.z, a[cc]);
                    a[cc] = fmaf(w4.w, ov.w, a[cc]);
                }
            }
#pragma unroll
            for (int cc = 0; cc < 4; ++cc) {
                float s = wave_sum(a[cc]);
                if (lane == 0)
                    ypart[(size_t)q * 16384 + b * 256 + c0 + cc] = s;
            }
        }
    }
    __syncthreads();
    if (tid == 0) rel_flag(uf + blk * 16);

    // ---- local sync: only the 4 blocks of this b ----
    if (tid < 4) spin_flag(uf + (b * 4 + tid) * 16);
    __syncthreads();

    // ---- P4: redundant per-b RMS + g; stream out quarter ----
    {
        float* g    = coef;                // reuse LDS
        float* wred = coef + 320;
        float yb = 0.f;
        if (tid < 256) {
            yb = out_b[tid] +
                 ypart[b * 256 + tid] + ypart[16384 + b * 256 + tid] +
                 ypart[32768 + b * 256 + tid] + ypart[49152 + b * 256 + tid];
            float v2 = wave_sum(yb * yb);
            if (lane == 0) wred[wv] = v2;
        }
        __syncthreads();
        float inv2 = rsqrtf((wred[0] + wred[1] + wred[2] + wred[3]) *
                            (1.0f / 256.0f) + EPSV);
        if (tid < 256) g[tid] = yb * inv2 * onorm[tid];
        __syncthreads();

        const float4* xx = reinterpret_cast<const float4*>(x) + (size_t)b * 16384;
        float4* oo = reinterpret_cast<float4*>(out) + (size_t)b * 16384;
#pragma unroll
        for (int r = 0; r < 4; ++r) {
            int c = r * 64 + (tid >> 4);
            int i = tid & 15;
            size_t idx = (size_t)c * 64 + q * 16 + i;
            float4 xv = xx[idx];
            float gg = g[c];
            oo[idx] = make_float4(xv.x + gg, xv.y + gg, xv.z + gg, xv.w + gg);
        }
    }
}

extern "C" void kernel_launch(void* const* d_in, const int* in_sizes, int n_in,
                              void* d_out, int out_size, void* d_ws, size_t ws_size,
                              hipStream_t stream) {
    const float* x     = (const float*)d_in[0];
    const float* temb  = (const float*)d_in[1];
    const float* mlp_w = (const float*)d_in[2];
    const float* mlp_b = (const float*)d_in[3];
    const float* qkv_w = (const float*)d_in[4];
    const float* out_w = (const float*)d_in[5];
    const float* out_b = (const float*)d_in[6];
    const float* onorm = (const float*)d_in[7];
    float* out = (float*)d_out;
    float* ws  = (float*)d_ws;

    float* scsh = ws + 69632;    // [64 b][512 j]  32768
    float* wvg  = ws + 102400;   // [8 h][256 c]   2048
    // ws[0..4095]      : flags (zeroed per call)
    // ws[4096..69631]  : ypart [4][64][256]

    hipMemsetAsync(ws, 0, 16384, stream);   // flag region (SDMA, ~free)
    k0_prep<<<1056, 256,  0, stream>>>(temb, mlp_w, mlp_b, qkv_w, scsh, wvg);
    k1_body<<<256,  1024, 0, stream>>>(x, scsh, wvg, out_w, out_b, onorm,
                                       out, ws);
}

// Round 11
// 37.212 us; speedup vs baseline: 1.3205x; 1.1002x over previous
//
#include <hip/hip_runtime.h>
#include <math.h>

// B=64, C=256, HW=256, HEADS=8, HEAD_DIM=256, HID=2048, TEMB=512
// Identity: einsum 'bhnm,bhcl->bhml' contracts n,c independently =>
// softmaxes sum to 1 => q,k irrelevant; pre-projection output is
// SC^2 * colsum of v over head_dim, constant over spatial l.
//
// Structure locked at 3 kernels (R8=35us; all sync/fusion variants lost:
// R3/R4 global barriers ~25us, R6 flag barrier ~13us, R9 convoy, R10 local
// sync +6us). This round: k1 at 2 blocks/CU (m-octant split), serial
// phases parallelized.

static constexpr float EPSV = 1e-6f;
static constexpr float SC2 = 1.0f / 256.0f;   // SC^2, SC = 256^-0.5

__device__ __forceinline__ float wave_sum(float v) {
    v += __shfl_xor(v, 1);  v += __shfl_xor(v, 2);
    v += __shfl_xor(v, 4);  v += __shfl_xor(v, 8);
    v += __shfl_xor(v, 16); v += __shfl_xor(v, 32);
    return v;
}

// ---------------- K0: time-MLP + Wv column-sums (R8 verbatim) -----------
__global__ void __launch_bounds__(256) k0_prep(
    const float* __restrict__ temb, const float* __restrict__ mlp_w,
    const float* __restrict__ mlp_b, const float* __restrict__ qkv_w,
    float* __restrict__ scsh, float* __restrict__ wvg)
{
    const int blk = blockIdx.x, tid = threadIdx.x;
    const int wv = tid >> 6, lane = tid & 63;
    if (blk < 1024) {
        int b = blk >> 4, jg = blk & 15;
        __shared__ float sl[512];
        float v0 = temb[b * 512 + tid];
        float v1 = temb[b * 512 + 256 + tid];
        sl[tid] = v0 / (1.0f + expf(-v0));
        sl[256 + tid] = v1 / (1.0f + expf(-v1));
        __syncthreads();
        int j0 = jg * 32 + wv * 8;
        float acc[8] = {0, 0, 0, 0, 0, 0, 0, 0};
        const float* wb = mlp_w + (size_t)j0 * 512 + lane;
#pragma unroll
        for (int k = 0; k < 8; ++k) {
            float sv = sl[k * 64 + lane];
#pragma unroll
            for (int jj = 0; jj < 8; ++jj)
                acc[jj] = fmaf(wb[(size_t)jj * 512 + k * 64], sv, acc[jj]);
        }
#pragma unroll
        for (int jj = 0; jj < 8; ++jj) {
            float a = wave_sum(acc[jj]);
            if (lane == 0) scsh[b * 512 + j0 + jj] = a + mlp_b[j0 + jj];
        }
    } else {
        int w = blk - 1024;                // 0..31
        int h = w >> 2, cq = w & 3;
        __shared__ float sm[256];
        const float* base =
            qkv_w + (size_t)(4096 + h * 256 + wv * 64) * 256 + cq * 64 + lane;
        float s = 0.f;
#pragma unroll 8
        for (int r = 0; r < 64; ++r) s += base[(size_t)r * 256];
        sm[wv * 64 + lane] = s;
        __syncthreads();
        if (tid < 64)
            wvg[h * 256 + cq * 64 + tid] =
                sm[tid] + sm[64 + tid] + sm[128 + tid] + sm[192 + tid];
    }
}

// ---------------- K1: x-pass + projection partials (m-octant) -----------
// grid 512 = (b, oc = m-octant of 32); 1024 threads; 2 blocks/CU.
__global__ void __launch_bounds__(1024) k1_body(
    const float* __restrict__ x, const float* __restrict__ scsh,
    const float* __restrict__ wvg, const float* __restrict__ out_w,
    float* __restrict__ ypart)
{
    const int blk = blockIdx.x, tid = threadIdx.x;
    const int wv = tid >> 6, lane = tid & 63;
    const int b = blk >> 3, oc = blk & 7;  // oc == XCD id -> out_w slice
                                           // L2-resident per XCD

    __shared__ float coef[256 * 8];        // [c][h]          8 KB
    __shared__ float apart[32 * 32 * 9];   // [cg][m][A0..7,ss2] 36 KB
    __shared__ float finbuf[32 * 9];       // [m][9]
    __shared__ float ofl[256];             // [h][m-oct]
    __shared__ float ssh[8];
    __shared__ float parts[8 * 4];         // [h][c-quarter]

    // ---- P1: coef/ssh, all 1024 threads (c = tid&255, h-pair = tid>>8) --
    {
        int c = tid & 255, hp = tid >> 8;
        float sc = 1.0f + scsh[b * 512 + c];
        float sh = scsh[b * 512 + 256 + c];
#pragma unroll
        for (int e = 0; e < 2; ++e) {
            int h = hp * 2 + e;
            float wvv = wvg[h * 256 + c];
            coef[c * 8 + h] = sc * wvv;
            float sv = wave_sum(sh * wvv);
            if (lane == 0) parts[h * 4 + (wv & 3)] = sv;
        }
    }
    __syncthreads();
    if (tid < 8)
        ssh[tid] = parts[tid * 4 + 0] + parts[tid * 4 + 1] +
                   parts[tid * 4 + 2] + parts[tid * 4 + 3];

    // ---- P2: x-pass over m-octant (m = tid&31, cg = tid>>5, 8 c each) ---
    {
        int m = tid & 31, cg = tid >> 5;
        float A[8] = {0, 0, 0, 0, 0, 0, 0, 0};
        float ss2 = 0.f;
        const float* xb = x + (size_t)b * 65536 + oc * 32 + m;
#pragma unroll
        for (int ci = 0; ci < 8; ++ci) {
            int c = cg * 8 + ci;
            float xv = xb[(size_t)c * 256];
            ss2 = fmaf(xv, xv, ss2);
            const float4 c0 = *reinterpret_cast<const float4*>(&coef[c * 8]);
            const float4 c1 = *reinterpret_cast<const float4*>(&coef[c * 8 + 4]);
            A[0] = fmaf(xv, c0.x, A[0]); A[1] = fmaf(xv, c0.y, A[1]);
            A[2] = fmaf(xv, c0.z, A[2]); A[3] = fmaf(xv, c0.w, A[3]);
            A[4] = fmaf(xv, c1.x, A[4]); A[5] = fmaf(xv, c1.y, A[5]);
            A[6] = fmaf(xv, c1.z, A[6]); A[7] = fmaf(xv, c1.w, A[7]);
        }
        float* ap = apart + ((size_t)cg * 32 + m) * 9;
#pragma unroll
        for (int h = 0; h < 8; ++h) ap[h] = A[h];
        ap[8] = ss2;
    }
    __syncthreads();

    // ---- reduce over 32 cg: 288 threads (m = tid&31, i = tid>>5) --------
    if (tid < 288) {
        int m = tid & 31, i = tid >> 5;
        float s = 0.f;
#pragma unroll
        for (int cg = 0; cg < 32; ++cg)
            s += apart[((size_t)cg * 32 + m) * 9 + i];
        finbuf[m * 9 + i] = s;
    }
    __syncthreads();

    // ---- of[h][m]: 256 threads (h = tid>>5, m = tid&31) -----------------
    if (tid < 256) {
        int h = tid >> 5, m = tid & 31;
        float inv = rsqrtf(finbuf[m * 9 + 8] * (1.0f / 256.0f) + EPSV);
        ofl[h * 32 + m] = SC2 * fmaf(inv, finbuf[m * 9 + h], ssh[h]);
    }
    __syncthreads();

    // ---- P3: ypart[oc][b][c] = sum_{h, m in oct} of*out_w[c][h*256+..] --
    {
        const float4* of4 = reinterpret_cast<const float4*>(ofl);  // [64]
        int h = lane >> 3, mm4 = lane & 7;
        const float4 ov = of4[lane];
        const size_t wbase = (size_t)h * 256 + oc * 32 + mm4 * 4;
#pragma unroll
        for (int g4 = 0; g4 < 4; ++g4) {
            int c0 = wv * 16 + g4 * 4;
            float a[4] = {0, 0, 0, 0};
#pragma unroll
            for (int cc = 0; cc < 4; ++cc) {
                const float4 w4 = *reinterpret_cast<const float4*>(
                    &out_w[(size_t)(c0 + cc) * 2048 + wbase]);
                a[cc] = fmaf(w4.x, ov.x, a[cc]);
                a[cc] = fmaf(w4.y, ov.y, a[cc]);
                a[cc] = fmaf(w4.z, ov.z, a[cc]);
                a[cc] = fmaf(w4.w, ov.w, a[cc]);
            }
#pragma unroll
            for (int cc = 0; cc < 4; ++cc) {
                float s = wave_sum(a[cc]);
                if (lane == 0)
                    ypart[(size_t)oc * 16384 + b * 256 + c0 + cc] = s;
            }
        }
    }
}

// ---------------- K2: reduce + RMS + g, wide stream ---------------------
__global__ void __launch_bounds__(256) k2_fin(
    const float* __restrict__ ypart, const float* __restrict__ out_b,
    const float* __restrict__ onorm, const float* __restrict__ x,
    float* __restrict__ out)
{
    const int blk = blockIdx.x, tid = threadIdx.x;
    const int b = blk >> 5, ch = blk & 31;
    __shared__ float gl[256];
    __shared__ float wred[4];
    float yb = out_b[tid];
#pragma unroll
    for (int oc = 0; oc < 8; ++oc)
        yb += ypart[(size_t)oc * 16384 + b * 256 + tid];
    float v2 = wave_sum(yb * yb);
    if ((tid & 63) == 0) wred[tid >> 6] = v2;
    __syncthreads();
    float inv2 = rsqrtf((wred[0] + wred[1] + wred[2] + wred[3]) *
                        (1.0f / 256.0f) + EPSV);
    gl[tid] = yb * inv2 * onorm[tid];
    __syncthreads();

    const float4* xx = reinterpret_cast<const float4*>(x) +
                       (size_t)b * 16384 + ch * 512;
    float4* oo = reinterpret_cast<float4*>(out) + (size_t)b * 16384 + ch * 512;
#pragma unroll
    for (int k = 0; k < 2; ++k) {
        int i = k * 256 + tid;
        int row = (ch * 512 + i) >> 6;
        float4 xv = xx[i];
        float gg = gl[row];
        oo[i] = make_float4(xv.x + gg, xv.y + gg, xv.z + gg, xv.w + gg);
    }
}

extern "C" void kernel_launch(void* const* d_in, const int* in_sizes, int n_in,
                              void* d_out, int out_size, void* d_ws, size_t ws_size,
                              hipStream_t stream) {
    const float* x     = (const float*)d_in[0];
    const float* temb  = (const float*)d_in[1];
    const float* mlp_w = (const float*)d_in[2];
    const float* mlp_b = (const float*)d_in[3];
    const float* qkv_w = (const float*)d_in[4];
    const float* out_w = (const float*)d_in[5];
    const float* out_b = (const float*)d_in[6];
    const float* onorm = (const float*)d_in[7];
    float* out = (float*)d_out;
    float* ws  = (float*)d_ws;

    float* scsh  = ws;            // [64 b][512 j]       32768
    float* wvg   = ws + 32768;    // [8 h][256 c]        2048
    float* ypart = ws + 34816;    // [8 oc][64 b][256 c] 131072

    k0_prep<<<1056, 256,  0, stream>>>(temb, mlp_w, mlp_b, qkv_w, scsh, wvg);
    k1_body<<<512,  1024, 0, stream>>>(x, scsh, wvg, out_w, ypart);
    k2_fin <<<2048, 256,  0, stream>>>(ypart, out_b, onorm, x, out);
}

// Round 12
// 32.074 us; speedup vs baseline: 1.5320x; 1.1602x over previous
//
#include <hip/hip_runtime.h>
#include <math.h>

// B=64, C=256, HW=256, HEADS=8, HEAD_DIM=256, HID=2048, TEMB=512
// Identity: einsum 'bhnm,bhcl->bhml' contracts n,c independently =>
// softmaxes sum to 1 => q,k irrelevant; pre-projection output is
// SC^2 * colsum of v over head_dim, constant over spatial l.
//
// Structure locked: 3 kernels, no cross-block sync (R8 = 35us best;
// every sync/fusion variant lost: global barrier ~25us, flag barrier
// ~13us, per-b 4-flag sync +6us, global convoy +14us). This round:
// R8 revert + intra-kernel polish only (wider P1/reduce in k1, fewer
// redundant RMS blocks in k2).

static constexpr float EPSV = 1e-6f;
static constexpr float SC2 = 1.0f / 256.0f;   // SC^2, SC = 256^-0.5

__device__ __forceinline__ float wave_sum(float v) {
    v += __shfl_xor(v, 1);  v += __shfl_xor(v, 2);
    v += __shfl_xor(v, 4);  v += __shfl_xor(v, 8);
    v += __shfl_xor(v, 16); v += __shfl_xor(v, 32);
    return v;
}

// ---------------- K0: time-MLP + Wv column-sums (R8 verbatim) -----------
__global__ void __launch_bounds__(256) k0_prep(
    const float* __restrict__ temb, const float* __restrict__ mlp_w,
    const float* __restrict__ mlp_b, const float* __restrict__ qkv_w,
    float* __restrict__ scsh, float* __restrict__ wvg)
{
    const int blk = blockIdx.x, tid = threadIdx.x;
    const int wv = tid >> 6, lane = tid & 63;
    if (blk < 1024) {
        int b = blk >> 4, jg = blk & 15;
        __shared__ float sl[512];
        float v0 = temb[b * 512 + tid];
        float v1 = temb[b * 512 + 256 + tid];
        sl[tid] = v0 / (1.0f + expf(-v0));
        sl[256 + tid] = v1 / (1.0f + expf(-v1));
        __syncthreads();
        int j0 = jg * 32 + wv * 8;
        float acc[8] = {0, 0, 0, 0, 0, 0, 0, 0};
        const float* wb = mlp_w + (size_t)j0 * 512 + lane;
#pragma unroll
        for (int k = 0; k < 8; ++k) {
            float sv = sl[k * 64 + lane];
#pragma unroll
            for (int jj = 0; jj < 8; ++jj)
                acc[jj] = fmaf(wb[(size_t)jj * 512 + k * 64], sv, acc[jj]);
        }
#pragma unroll
        for (int jj = 0; jj < 8; ++jj) {
            float a = wave_sum(acc[jj]);
            if (lane == 0) scsh[b * 512 + j0 + jj] = a + mlp_b[j0 + jj];
        }
    } else {
        int w = blk - 1024;                // 0..31
        int h = w >> 2, cq = w & 3;
        __shared__ float sm[256];
        const float* base =
            qkv_w + (size_t)(4096 + h * 256 + wv * 64) * 256 + cq * 64 + lane;
        float s = 0.f;
#pragma unroll 8
        for (int r = 0; r < 64; ++r) s += base[(size_t)r * 256];
        sm[wv * 64 + lane] = s;
        __syncthreads();
        if (tid < 64)
            wvg[h * 256 + cq * 64 + tid] =
                sm[tid] + sm[64 + tid] + sm[128 + tid] + sm[192 + tid];
    }
}

// ---------------- K1: x-pass + projection partials (R8 + polish) --------
// grid 256 = (b, q = m-quarter of 64); 1024 threads.
__global__ void __launch_bounds__(1024) k1_body(
    const float* __restrict__ x, const float* __restrict__ scsh,
    const float* __restrict__ wvg, const float* __restrict__ out_w,
    float* __restrict__ ypart)
{
    const int blk = blockIdx.x, tid = threadIdx.x;
    const int wv = tid >> 6, lane = tid & 63;
    const int b = blk >> 2, q = blk & 3;

    __shared__ float coef[256 * 8];        // [c][h]  8 KB
    __shared__ float apart[16 * 64 * 9];   // [cg][m][A0..7,ss2]  36 KB
    __shared__ float finbuf[64 * 9];       // [m][9]
    __shared__ float ofl[512];             // [h][m]  2 KB
    __shared__ float ssh[8];
    __shared__ float parts[8 * 4];         // [h][c-quarter]

    // ---- P1: coef/ssh with all 1024 threads (c = tid&255, hp = tid>>8) --
    {
        int c = tid & 255, hp = tid >> 8;
        float sc = 1.0f + scsh[b * 512 + c];
        float sh = scsh[b * 512 + 256 + c];
#pragma unroll
        for (int e = 0; e < 2; ++e) {
            int h = hp * 2 + e;
            float wvv = wvg[h * 256 + c];
            coef[c * 8 + h] = sc * wvv;
            float sv = wave_sum(sh * wvv);
            if (lane == 0) parts[h * 4 + (wv & 3)] = sv;
        }
    }
    __syncthreads();
    if (tid < 8)
        ssh[tid] = parts[tid * 4 + 0] + parts[tid * 4 + 1] +
                   parts[tid * 4 + 2] + parts[tid * 4 + 3];

    // ---- P2: x-pass over m-quarter q (m = tid&63, cg = tid>>6) ----------
    {
        int m = tid & 63, cg = tid >> 6;   // 16 c-groups x 16 c
        float A[8] = {0, 0, 0, 0, 0, 0, 0, 0};
        float ss2 = 0.f;
        const float* xb = x + (size_t)b * 65536 + q * 64 + m;
#pragma unroll
        for (int ci = 0; ci < 16; ++ci) {
            int c = cg * 16 + ci;
            float xv = xb[(size_t)c * 256];
            ss2 = fmaf(xv, xv, ss2);
            const float4 c0 = *reinterpret_cast<const float4*>(&coef[c * 8]);
            const float4 c1 = *reinterpret_cast<const float4*>(&coef[c * 8 + 4]);
            A[0] = fmaf(xv, c0.x, A[0]); A[1] = fmaf(xv, c0.y, A[1]);
            A[2] = fmaf(xv, c0.z, A[2]); A[3] = fmaf(xv, c0.w, A[3]);
            A[4] = fmaf(xv, c1.x, A[4]); A[5] = fmaf(xv, c1.y, A[5]);
            A[6] = fmaf(xv, c1.z, A[6]); A[7] = fmaf(xv, c1.w, A[7]);
        }
        float* ap = apart + ((size_t)cg * 64 + m) * 9;
#pragma unroll
        for (int h = 0; h < 8; ++h) ap[h] = A[h];
        ap[8] = ss2;
    }
    __syncthreads();

    // ---- reduce over 16 cg: 576 threads (m = tid&63, i = tid/64) --------
    if (tid < 576) {
        int m = tid & 63, i = tid >> 6;    // i = 0..8
        float s = 0.f;
#pragma unroll
        for (int cg = 0; cg < 16; ++cg)
            s += apart[((size_t)cg * 64 + m) * 9 + i];
        finbuf[m * 9 + i] = s;
    }
    __syncthreads();

    // ---- of[h][m]: 512 threads (h = tid>>6, m = tid&63) -----------------
    if (tid < 512) {
        int h = tid >> 6, m = tid & 63;
        float inv = rsqrtf(finbuf[m * 9 + 8] * (1.0f / 256.0f) + EPSV);
        ofl[h * 64 + m] = SC2 * fmaf(inv, finbuf[m * 9 + h], ssh[h]);
    }
    __syncthreads();

    // ---- P3: projection partial -> ypart[q][b][c] -----------------------
    {
        const float4* of4 = reinterpret_cast<const float4*>(ofl);  // [128]
#pragma unroll
        for (int g4 = 0; g4 < 4; ++g4) {
            int c0 = wv * 16 + g4 * 4;
            float a[4] = {0, 0, 0, 0};
#pragma unroll
            for (int cc = 0; cc < 4; ++cc) {
                int c = c0 + cc;
#pragma unroll
                for (int k = 0; k < 2; ++k) {
                    int idx = k * 64 + lane;       // 0..127
                    int h = idx >> 4, mm = (idx & 15) * 4;
                    const float4 w4 = *reinterpret_cast<const float4*>(
                        &out_w[(size_t)c * 2048 + h * 256 + q * 64 + mm]);
                    float4 ov = of4[idx];
                    a[cc] = fmaf(w4.x, ov.x, a[cc]);
                    a[cc] = fmaf(w4.y, ov.y, a[cc]);
                    a[cc] = fmaf(w4.z, ov.z, a[cc]);
                    a[cc] = fmaf(w4.w, ov.w, a[cc]);
                }
            }
#pragma unroll
            for (int cc = 0; cc < 4; ++cc) {
                float s = wave_sum(a[cc]);
                if (lane == 0)
                    ypart[(size_t)q * 16384 + b * 256 + c0 + cc] = s;
            }
        }
    }
}

// ---------------- K2: reduce + RMS + g, wide stream ---------------------
// grid 512 = (b, ch of 8); 1024 thr. 8 redundant RMS per b (was 32).
__global__ void __launch_bounds__(1024) k2_fin(
    const float* __restrict__ ypart, const float* __restrict__ out_b,
    const float* __restrict__ onorm, const float* __restrict__ x,
    float* __restrict__ out)
{
    const int blk = blockIdx.x, tid = threadIdx.x;
    const int b = blk >> 3, ch = blk & 7;
    __shared__ float gl[256];
    __shared__ float wred[4];
    if (tid < 256) {
        float yb = out_b[tid] +
                   ypart[b * 256 + tid] + ypart[16384 + b * 256 + tid] +
                   ypart[32768 + b * 256 + tid] + ypart[49152 + b * 256 + tid];
        float v2 = wave_sum(yb * yb);
        if ((tid & 63) == 0) wred[tid >> 6] = v2;
        gl[tid] = yb;
    }
    __syncthreads();
    {
        float inv2 = rsqrtf((wred[0] + wred[1] + wred[2] + wred[3]) *
                            (1.0f / 256.0f) + EPSV);
        if (tid < 256) gl[tid] = gl[tid] * inv2 * onorm[tid];
    }
    __syncthreads();

    const float4* xx = reinterpret_cast<const float4*>(x) +
                       (size_t)b * 16384 + ch * 2048;
    float4* oo = reinterpret_cast<float4*>(out) + (size_t)b * 16384 + ch * 2048;
#pragma unroll
    for (int k = 0; k < 2; ++k) {
        int i = k * 1024 + tid;
        int row = (ch * 2048 + i) >> 6;
        float4 xv = xx[i];
        float gg = gl[row];
        oo[i] = make_float4(xv.x + gg, xv.y + gg, xv.z + gg, xv.w + gg);
    }
}

extern "C" void kernel_launch(void* const* d_in, const int* in_sizes, int n_in,
                              void* d_out, int out_size, void* d_ws, size_t ws_size,
                              hipStream_t stream) {
    const float* x     = (const float*)d_in[0];
    const float* temb  = (const float*)d_in[1];
    const float* mlp_w = (const float*)d_in[2];
    const float* mlp_b = (const float*)d_in[3];
    const float* qkv_w = (const float*)d_in[4];
    const float* out_w = (const float*)d_in[5];
    const float* out_b = (const float*)d_in[6];
    const float* onorm = (const float*)d_in[7];
    float* out = (float*)d_out;
    float* ws  = (float*)d_ws;

    float* scsh  = ws;            // [64 b][512 j]       32768
    float* wvg   = ws + 32768;    // [8 h][256 c]        2048
    float* ypart = ws + 34816;    // [4 q][64 b][256 c]  65536

    k0_prep<<<1056, 256,  0, stream>>>(temb, mlp_w, mlp_b, qkv_w, scsh, wvg);
    k1_body<<<256,  1024, 0, stream>>>(x, scsh, wvg, out_w, ypart);
    k2_fin <<<512,  1024, 0, stream>>>(ypart, out_b, onorm, x, out);
}